// Round 9
// baseline (174.412 us; speedup 1.0000x reference)
//
#include <hip/hip_runtime.h>
#include <math.h>

#define NI 128
#define NC 256
#define NR 36
#define NW 48
#define ND 256

#define PIB 264      // sIb pitch (bf16): 528 B rows -> 2-way banks on b128 reads: free
#define PG  72       // sG pitch: 144 B rows, 2-way banks; cols 36..71 stay zero (k-pad)
#define PSP 52       // sP pitch: quad write-offsets {0,8,16,24} banks -> conflict-free writes;
                     // read spans 2-way overlap (free). 2x16-row buffers/wave (W/R pipeline).

// lambda_softmax(9) * log2(e); lambda_lse(6) * log2(e)
#define SOFT_SCALE 12.984255368000671f
#define LSE_SCALE   8.656170245333781f

typedef __bf16 bf16;
typedef __bf16 bf16x8 __attribute__((ext_vector_type(8)));
typedef __bf16 bf16x4 __attribute__((ext_vector_type(4)));
typedef float  f32x4  __attribute__((ext_vector_type(4)));

// LDS carve (bytes) — 37632 total (R8 carve, proven: 4-block LDS cap, ~3.3 measured)
#define OFF_IB    0        // 36*264*2 = 19008
#define OFF_G     19008    // 36*72*2  = 5184  -> 24192
#define OFF_P     24192    // 4 waves x 2 buffers x 16*52*2 = 13312 -> 37504
#define OFF_GUARD 37504    // 128 B zero tail (row-15 pa1 overread of last wave's bufB)
#define SMEM_TOTAL 37632

#define MFMA16(A,B,C) __builtin_amdgcn_mfma_f32_16x16x32_bf16(A, B, C, 0, 0, 0)

__device__ __forceinline__ float dpp_add16(float v) {
    int x = __builtin_bit_cast(int, v);
    v += __builtin_bit_cast(float, __builtin_amdgcn_update_dpp(0, x, 0xB1, 0xF, 0xF, true));
    x = __builtin_bit_cast(int, v);
    v += __builtin_bit_cast(float, __builtin_amdgcn_update_dpp(0, x, 0x4E, 0xF, 0xF, true));
    x = __builtin_bit_cast(int, v);
    v += __builtin_bit_cast(float, __builtin_amdgcn_update_dpp(0, x, 0x141, 0xF, 0xF, true));
    x = __builtin_bit_cast(int, v);
    v += __builtin_bit_cast(float, __builtin_amdgcn_update_dpp(0, x, 0x140, 0xF, 0xF, true));
    return v;
}

// leaky_relu(0.1) as 2 VALU ops: 0.55t + 0.45|t|
__device__ __forceinline__ float lrelu(float t) {
    return __builtin_fmaf(0.55f, t, 0.45f * __builtin_fabsf(t));
}

// ---- prep: captions fp32 -> bf16 cache + per-caption-row LSE_SCALE/||row|| ----
__global__ __launch_bounds__(256)
void prep_kernel(const float* __restrict__ captions, bf16* __restrict__ capb,
                 float* __restrict__ w1g)
{
    const int c = blockIdx.x >> 2, q = blockIdx.x & 3;
    const int wave = threadIdx.x >> 6, lane = threadIdx.x & 63;
    #pragma unroll
    for (int j = 0; j < 3; ++j) {
        int w = q * 12 + wave * 3 + j;
        size_t off = ((size_t)c * NW + w) * ND + lane * 4;
        float4 v = *(const float4*)(captions + off);
        bf16x4 h = { (bf16)v.x, (bf16)v.y, (bf16)v.z, (bf16)v.w };
        *(bf16x4*)(capb + off) = h;
        float s = v.x*v.x + v.y*v.y + v.z*v.z + v.w*v.w;
        s += __shfl_xor(s, 1);  s += __shfl_xor(s, 2);  s += __shfl_xor(s, 4);
        s += __shfl_xor(s, 8);  s += __shfl_xor(s, 16); s += __shfl_xor(s, 32);
        if (lane == 0) w1g[c * NW + w] = LSE_SCALE / sqrtf(s);
    }
}

__device__ __forceinline__ bf16x8 ld_cvt_f32(const float* p, float& ss) {
    float4 lo = *(const float4*)p;
    float4 hi = *(const float4*)(p + 4);
    ss += lo.x*lo.x + lo.y*lo.y + lo.z*lo.z + lo.w*lo.w
        + hi.x*hi.x + hi.y*hi.y + hi.z*hi.z + hi.w*hi.w;
    bf16x8 r = { (bf16)lo.x, (bf16)lo.y, (bf16)lo.z, (bf16)lo.w,
                 (bf16)hi.x, (bf16)hi.y, (bf16)hi.z, (bf16)hi.w };
    return r;
}

// W-stage: softmax weights for one mt-tile -> IN-PLACE into ACC[MT] + write to sP buffer.
#define STAGE_W(ACC, MT, BUF, W12) do {                                                 \
    _Pragma("unroll")                                                                   \
    for (int p = 0; p < 4; ++p) {                                                       \
        float a0v = ACC[MT][0][p], a1v = ACC[MT][1][p], a2v = ACC[MT][2][p];            \
        float e0 = exp2f(__builtin_fmaf(c1[0], a0v, c2[0] * __builtin_fabsf(a0v)));     \
        float e1 = exp2f(__builtin_fmaf(c1[1], a1v, c2[1] * __builtin_fabsf(a1v)));     \
        float e2 = (l15 >= 12)                                                          \
            ? exp2f(__builtin_fmaf(c1[2], a2v, c2[2] * __builtin_fabsf(a2v)))           \
            : 0.f;                                        /* r=32..35 only */           \
        W12[p] = e0 * a0v + e1 * a1v + e2 * a2v;                                        \
        ACC[MT][0][p] = e0; ACC[MT][1][p] = e1; ACC[MT][2][p] = e2;   /* in-place */    \
        int row = quad * 4 + p;                                                         \
        (BUF)[row * PSP + l15]      = (bf16)e0;                                         \
        (BUF)[row * PSP + 16 + l15] = (bf16)e1;                                         \
        if (l15 >= 12) (BUF)[row * PSP + rb2 + l15] = (bf16)e2;   /* cols 32..35 */     \
    }                                                                                   \
} while (0)

// R-stage: PV MFMA via Gram + epilogue. Reads BUF written >=1 full stage earlier.
#define STAGE_R(ACC, MT, BUF, W12) do {                                                 \
    const bf16* ap = (BUF) + l15 * PSP;                                                 \
    bf16x8 pa0 = *(const bf16x8*)(ap + quad * 8);                                       \
    bf16x8 pa1 = *(const bf16x8*)(ap + 32 + quad * 8);  /* cols>=36: finite x G-zeros */\
    f32x4 pg0 = {0,0,0,0}, pg1 = {0,0,0,0}, pg2 = {0,0,0,0};                            \
    {                                                                                   \
        bf16x8 t0 = *(const bf16x8*)&sG[(l15) * PG + quad * 8];                         \
        bf16x8 t1 = *(const bf16x8*)&sG[(l15) * PG + 32 + quad * 8];                    \
        pg0 = MFMA16(pa0, t0, pg0); pg0 = MFMA16(pa1, t1, pg0);                         \
        bf16x8 t2 = *(const bf16x8*)&sG[(16 + l15) * PG + quad * 8];                    \
        bf16x8 t3 = *(const bf16x8*)&sG[(16 + l15) * PG + 32 + quad * 8];               \
        pg1 = MFMA16(pa0, t2, pg1); pg1 = MFMA16(pa1, t3, pg1);                         \
        bf16x8 t4 = *(const bf16x8*)&sG[(rb2 + l15) * PG + quad * 8];                   \
        bf16x8 t5 = *(const bf16x8*)&sG[(rb2 + l15) * PG + 32 + quad * 8];              \
        pg2 = MFMA16(pa0, t4, pg2); pg2 = MFMA16(pa1, t5, pg2);                         \
    }                                                                                   \
    float4 wq = {0.f, 0.f, 0.f, 0.f};                                                   \
    if constexpr (USE_WS)                                                               \
        wq = *(const float4*)&w1g[(size_t)c * NW + (MT) * 16 + quad * 4];               \
    _Pragma("unroll")                                                                   \
    for (int p = 0; p < 4; ++p) {                                                       \
        float s2 = pg0[p] * ACC[MT][0][p] + pg1[p] * ACC[MT][1][p]                      \
                 + pg2[p] * ACC[MT][2][p];                    /* ACC holds e (f32) */   \
        s2 = dpp_add16(s2);                                                             \
        float w12 = dpp_add16(W12[p]);                                                  \
        float wf = USE_WS ? ((const float*)&wq)[p] : w1f[MT][p];                        \
        esum += exp2f(w12 * __frsqrt_rn(fmaxf(s2, 1e-16f)) * wf);                       \
    }                                                                                   \
} while (0)

// Ledger: R8's W/R pipeline + in-place diet = first real win (122.4 -> 115.6 us).
// R9: cross-caption QK overlap at the SAFE positions — R3's null used the lgkm-poison
// slot (between sP writes and pa reads); here qk_steps go (a) under the norm phase
// (pure shfl/VALU) and (b) after each STAGE_R's MFMA block, where pa reads are already
// issued and in-order DS completion keeps the waits fine-grained. Dual acc bank =
// +36 regs -> waves_per_eu(3,8): budget ~170 = today's measured 3 waves/SIMD, no
// strangle (R1 lesson). Spill canary: WRITE_SIZE (~132 KB clean; MBs = revert).
template<bool USE_WS>
__global__ __attribute__((amdgpu_flat_work_group_size(256, 256), amdgpu_waves_per_eu(3, 8)))
void scan_main(const float* __restrict__ images,
               const float* __restrict__ captions,
               const bf16* __restrict__ capb,
               const float* __restrict__ w1g,
               float* __restrict__ out)
{
    __shared__ __align__(16) unsigned char smem[SMEM_TOTAL];
    bf16* sIb = (bf16*)(smem + OFF_IB);   // [r][d] image, 36 real rows only
    bf16* sG  = (bf16*)(smem + OFF_G);    // [r'][r] Gram, 36 rows x 72 cols (36..71 zero)

    const int tid  = threadIdx.x;
    const int wave = tid >> 6;
    const int lane = tid & 63;
    const int quad = lane >> 4;
    const int l15  = lane & 15;
    const int i    = blockIdx.x >> 4;
    const int c0   = (blockIdx.x & 15) * 16;  // chunk -> (chunk%8) XCD-affine captions

    bf16* bufA = (bf16*)(smem + OFF_P) + wave * (32 * PSP);   // two 16-row buffers
    bf16* bufB = bufA + 16 * PSP;

    const int rb2 = 20;   // r-tile bases {0,16,20}; tile 2 overlaps tile 1 on r=20..31

    // ---- init: stage image bf16, zero sG and sP+guard ----
    const float* gI = images + (size_t)i * NR * ND;
    #pragma unroll
    for (int k = 0; k < 9; ++k) {
        int t = tid + k * 256;               // 2304 float4
        int e = t * 4, r = e >> 8, d = e & 255;
        float4 v = *(const float4*)(gI + e);
        bf16x4 h = { (bf16)v.x, (bf16)v.y, (bf16)v.z, (bf16)v.w };
        *(bf16x4*)&sIb[r * PIB + d] = h;
    }
    {
        uint32_t* pG = (uint32_t*)sG;        // 1296 dwords
        #pragma unroll
        for (int k = 0; k < 6; ++k) { int x = tid + k * 256; if (x < 1296) pG[x] = 0u; }
        uint32_t* pP = (uint32_t*)(smem + OFF_P);   // sP buffers + guard: 3360 dwords
        #pragma unroll
        for (int k = 0; k < 14; ++k) { int x = tid + k * 256; if (x < 3360) pP[x] = 0u; }
        // cols 36..51 of each sP row are never written after this -> stay zero (k-pad safety)
    }
    __syncthreads();   // B0

    // ---- once: Gram G = I*I^T over overlapped m-tiles {0,16,20} (waves 0-2) ----
    if (wave < 3) {
        const int mb = (wave == 2) ? rb2 : wave * 16;
        f32x4 g0 = {0,0,0,0}, g1 = {0,0,0,0}, g2 = {0,0,0,0};
        #pragma unroll
        for (int ks = 0; ks < 8; ++ks) {
            bf16x8 a  = *(const bf16x8*)&sIb[(mb + l15)  * PIB + ks * 32 + quad * 8];
            bf16x8 b0 = *(const bf16x8*)&sIb[(l15)       * PIB + ks * 32 + quad * 8];
            bf16x8 b1 = *(const bf16x8*)&sIb[(16 + l15)  * PIB + ks * 32 + quad * 8];
            bf16x8 b2 = *(const bf16x8*)&sIb[(rb2 + l15) * PIB + ks * 32 + quad * 8];
            g0 = MFMA16(a, b0, g0); g1 = MFMA16(a, b1, g1); g2 = MFMA16(a, b2, g2);
        }
        // duplicate writes in overlap regions carry identical values (benign)
        #pragma unroll
        for (int p = 0; p < 4; ++p) {
            int m = mb + quad * 4 + p;
            sG[m * PG + l15]       = (bf16)g0[p];
            sG[m * PG + 16 + l15]  = (bf16)g1[p];
            sG[m * PG + rb2 + l15] = (bf16)g2[p];
        }
    }
    __syncthreads();   // B1: sG published. No further barriers.

    if constexpr (USE_WS) {
        // ================= pipelined path: W/R stages + cross-caption QK =================
        const size_t cstep = (size_t)NW * ND;
        const bf16* ab0 = capb + ((size_t)(c0 + wave * 4) * NW + l15) * ND + quad * 8;
        float w1f[3][4] = {};   // unused on this path (macro symbol)

        auto qk_step = [&](f32x4 (&A)[3][3], const bf16* ab, int ks) {
            bf16x8 a0 = *(const bf16x8*)(ab + ks * 32);
            bf16x8 a1 = *(const bf16x8*)(ab + 16 * ND + ks * 32);
            bf16x8 a2 = *(const bf16x8*)(ab + 32 * ND + ks * 32);
            bf16x8 b0 = *(const bf16x8*)&sIb[(l15)       * PIB + ks * 32 + quad * 8];
            bf16x8 b1 = *(const bf16x8*)&sIb[(16 + l15)  * PIB + ks * 32 + quad * 8];
            bf16x8 b2 = *(const bf16x8*)&sIb[(rb2 + l15) * PIB + ks * 32 + quad * 8];
            A[0][0] = MFMA16(a0, b0, A[0][0]);
            A[1][0] = MFMA16(a1, b0, A[1][0]);
            A[2][0] = MFMA16(a2, b0, A[2][0]);
            A[0][1] = MFMA16(a0, b1, A[0][1]);
            A[1][1] = MFMA16(a1, b1, A[1][1]);
            A[2][1] = MFMA16(a2, b1, A[2][1]);
            A[0][2] = MFMA16(a0, b2, A[0][2]);
            A[1][2] = MFMA16(a1, b2, A[1][2]);
            A[2][2] = MFMA16(a2, b2, A[2][2]);
        };

        f32x4 accP[3][3] = {}, accQ[3][3];
        #pragma unroll
        for (int ks = 0; ks < 8; ++ks) qk_step(accP, ab0, ks);   // prologue: caption 0

        #pragma unroll
        for (int it = 0; it < 4; ++it) {
            f32x4 (&cur)[3][3] = (it & 1) ? accQ : accP;   // compile-time parity
            f32x4 (&nxt)[3][3] = (it & 1) ? accP : accQ;
            const bf16* abn = ab0 + (size_t)(it + 1) * cstep;   // never deref'd at it==3
            const int c = c0 + wave * 4 + it;

            if (it < 3) {
                #pragma unroll
                for (int x = 0; x < 3; ++x)
                    #pragma unroll
                    for (int y = 0; y < 3; ++y) nxt[x][y] = (f32x4){0.f, 0.f, 0.f, 0.f};
            }

            // ---- norm phase (pure VALU/shfl): fold 9*log2e*inv -> exp2(c1*a + c2*|a|) ----
            float c1[3], c2[3];
            #pragma unroll
            for (int nt = 0; nt < 3; ++nt) {
                float s = 0.f;
                #pragma unroll
                for (int mt = 0; mt < 3; ++mt)
                    #pragma unroll
                    for (int p = 0; p < 4; ++p) { float t = lrelu(cur[mt][nt][p]); s += t * t; }
                s += __shfl_xor(s, 16); s += __shfl_xor(s, 32);
                float inv = SOFT_SCALE * __frsqrt_rn(fmaxf(s, 1e-12f));
                c1[nt] = 0.55f * inv;
                c2[nt] = 0.45f * inv;
            }
            // qk 0,1 of it+1 under the shfl chains (no other LDS ops in flight here)
            if (it < 3) { qk_step(nxt, abn, 0); qk_step(nxt, abn, 1); }

            // ---- W/R pipeline (R8 order); qk pairs AFTER each R's MFMA block ----
            float esum = 0.f;
            float w12a[4], w12b[4], w12c[4];
            STAGE_W(cur, 0, bufA, w12a);
            STAGE_W(cur, 1, bufB, w12b);
            STAGE_R(cur, 0, bufA, w12a);
            if (it < 3) { qk_step(nxt, abn, 2); qk_step(nxt, abn, 3); }
            STAGE_W(cur, 2, bufA, w12c);
            STAGE_R(cur, 1, bufB, w12b);
            if (it < 3) { qk_step(nxt, abn, 4); qk_step(nxt, abn, 5); }
            STAGE_R(cur, 2, bufA, w12c);
            if (it < 3) { qk_step(nxt, abn, 6); qk_step(nxt, abn, 7); }

            esum += __shfl_xor(esum, 16); esum += __shfl_xor(esum, 32);
            if (lane == 0) out[(size_t)i * NC + c] = logf(esum) * (1.0f / 6.0f);
        }
    } else {
        // ================= fallback (no workspace): R8 serial path =================
        for (int it = 0; it < 4; ++it) {
            const int c = c0 + wave * 4 + it;
            f32x4 acc[3][3] = {};
            float ssc[3] = {0.f, 0.f, 0.f};
            float w1f[3][4] = {};
            const float* ab32 = captions + ((size_t)c * NW + l15) * ND + quad * 8;
            #pragma unroll
            for (int ks = 0; ks < 8; ++ks) {
                bf16x8 a0 = ld_cvt_f32(ab32 + ks * 32, ssc[0]);
                bf16x8 a1 = ld_cvt_f32(ab32 + 16 * ND + ks * 32, ssc[1]);
                bf16x8 a2 = ld_cvt_f32(ab32 + 32 * ND + ks * 32, ssc[2]);
                bf16x8 b0 = *(const bf16x8*)&sIb[(l15)       * PIB + ks * 32 + quad * 8];
                bf16x8 b1 = *(const bf16x8*)&sIb[(16 + l15)  * PIB + ks * 32 + quad * 8];
                bf16x8 b2 = *(const bf16x8*)&sIb[(rb2 + l15) * PIB + ks * 32 + quad * 8];
                acc[0][0] = MFMA16(a0, b0, acc[0][0]);
                acc[1][0] = MFMA16(a1, b0, acc[1][0]);
                acc[2][0] = MFMA16(a2, b0, acc[2][0]);
                acc[0][1] = MFMA16(a0, b1, acc[0][1]);
                acc[1][1] = MFMA16(a1, b1, acc[1][1]);
                acc[2][1] = MFMA16(a2, b1, acc[2][1]);
                acc[0][2] = MFMA16(a0, b2, acc[0][2]);
                acc[1][2] = MFMA16(a1, b2, acc[1][2]);
                acc[2][2] = MFMA16(a2, b2, acc[2][2]);
            }
            #pragma unroll
            for (int mt = 0; mt < 3; ++mt) {
                float s = ssc[mt];
                s += __shfl_xor(s, 16); s += __shfl_xor(s, 32);
                ssc[mt] = LSE_SCALE * __frsqrt_rn(fmaxf(s, 1e-16f));
            }
            #pragma unroll
            for (int mt = 0; mt < 3; ++mt)
                #pragma unroll
                for (int p = 0; p < 4; ++p)
                    w1f[mt][p] = __shfl(ssc[mt], (lane & 48) + quad * 4 + p);

            float c1[3], c2[3];
            #pragma unroll
            for (int nt = 0; nt < 3; ++nt) {
                float s = 0.f;
                #pragma unroll
                for (int mt = 0; mt < 3; ++mt)
                    #pragma unroll
                    for (int p = 0; p < 4; ++p) { float t = lrelu(acc[mt][nt][p]); s += t * t; }
                s += __shfl_xor(s, 16); s += __shfl_xor(s, 32);
                float inv = SOFT_SCALE * __frsqrt_rn(fmaxf(s, 1e-12f));
                c1[nt] = 0.55f * inv; c2[nt] = 0.45f * inv;
            }

            float esum = 0.f;
            float w12a[4], w12b[4], w12c[4];
            STAGE_W(acc, 0, bufA, w12a);
            STAGE_W(acc, 1, bufB, w12b);
            STAGE_R(acc, 0, bufA, w12a);
            STAGE_W(acc, 2, bufA, w12c);
            STAGE_R(acc, 1, bufB, w12b);
            STAGE_R(acc, 2, bufA, w12c);

            esum += __shfl_xor(esum, 16); esum += __shfl_xor(esum, 32);
            if (lane == 0) out[(size_t)i * NC + c] = logf(esum) * (1.0f / 6.0f);
        }
    }
}

extern "C" void kernel_launch(void* const* d_in, const int* in_sizes, int n_in,
                              void* d_out, int out_size, void* d_ws, size_t ws_size,
                              hipStream_t stream) {
    const float* images   = (const float*)d_in[0];   // (128, 36, 256) fp32
    const float* captions = (const float*)d_in[1];   // (256, 48, 256) fp32
    float* out = (float*)d_out;                      // (128, 256) fp32

    const size_t need_w1  = (size_t)NC * NW * sizeof(float);   // 49152
    const size_t need_cap = (size_t)NC * NW * ND * 2;          // 6291456
    bool use_ws = ws_size >= need_w1 + need_cap;

    dim3 grid(2048), block(256);   // R2/R8 launch geometry (proven best)
    if (use_ws) {
        float* w1g = (float*)d_ws;
        bf16*  capb = (bf16*)((char*)d_ws + need_w1);
        hipLaunchKernelGGL(prep_kernel, dim3(1024), dim3(256), 0, stream, captions, capb, w1g);
        hipLaunchKernelGGL((scan_main<true>), grid, block, 0, stream, images, captions, capb, w1g, out);
    } else {
        hipLaunchKernelGGL((scan_main<false>), grid, block, 0, stream, images, captions,
                           (const bf16*)nullptr, (const float*)nullptr, out);
    }
}

// Round 10
// 164.126 us; speedup vs baseline: 1.0627x; 1.0627x over previous
//
#include <hip/hip_runtime.h>
#include <math.h>

#define NI 128
#define NC 256
#define NR 36
#define NW 48
#define ND 256

#define PIB 264      // sIb pitch (bf16): 528 B rows -> 2-way banks on b128 reads: free
#define PG  72       // sG pitch: 144 B rows, 2-way banks; cols 36..71 stay zero (k-pad)
#define PSP 52       // sP pitch: quad write-offsets {0,8,16,24} banks -> conflict-free writes;
                     // read spans 2-way overlap (free). 2x16-row buffers/wave (W/R pipeline).

// lambda_softmax(9) * log2(e); lambda_lse(6) * log2(e)
#define SOFT_SCALE 12.984255368000671f
#define LSE_SCALE   8.656170245333781f

typedef __bf16 bf16;
typedef __bf16 bf16x8 __attribute__((ext_vector_type(8)));
typedef __bf16 bf16x4 __attribute__((ext_vector_type(4)));
typedef float  f32x4  __attribute__((ext_vector_type(4)));

// LDS carve (bytes) — 37632 total (R8 carve, proven best: 115.6 us)
#define OFF_IB    0        // 36*264*2 = 19008
#define OFF_G     19008    // 36*72*2  = 5184  -> 24192
#define OFF_P     24192    // 4 waves x 2 buffers x 16*52*2 = 13312 -> 37504
#define OFF_GUARD 37504    // 128 B zero tail (row-15 pa1 overread of last wave's bufB)
#define SMEM_TOTAL 37632

#define MFMA16(A,B,C) __builtin_amdgcn_mfma_f32_16x16x32_bf16(A, B, C, 0, 0, 0)

__device__ __forceinline__ float dpp_add16(float v) {
    int x = __builtin_bit_cast(int, v);
    v += __builtin_bit_cast(float, __builtin_amdgcn_update_dpp(0, x, 0xB1, 0xF, 0xF, true));
    x = __builtin_bit_cast(int, v);
    v += __builtin_bit_cast(float, __builtin_amdgcn_update_dpp(0, x, 0x4E, 0xF, 0xF, true));
    x = __builtin_bit_cast(int, v);
    v += __builtin_bit_cast(float, __builtin_amdgcn_update_dpp(0, x, 0x141, 0xF, 0xF, true));
    x = __builtin_bit_cast(int, v);
    v += __builtin_bit_cast(float, __builtin_amdgcn_update_dpp(0, x, 0x140, 0xF, 0xF, true));
    return v;
}

// leaky_relu(0.1) as 2 VALU ops: 0.55t + 0.45|t|
__device__ __forceinline__ float lrelu(float t) {
    return __builtin_fmaf(0.55f, t, 0.45f * __builtin_fabsf(t));
}

// ---- prep: captions fp32 -> bf16 cache + per-caption-row LSE_SCALE/||row|| ----
__global__ __launch_bounds__(256)
void prep_kernel(const float* __restrict__ captions, bf16* __restrict__ capb,
                 float* __restrict__ w1g)
{
    const int c = blockIdx.x >> 2, q = blockIdx.x & 3;
    const int wave = threadIdx.x >> 6, lane = threadIdx.x & 63;
    #pragma unroll
    for (int j = 0; j < 3; ++j) {
        int w = q * 12 + wave * 3 + j;
        size_t off = ((size_t)c * NW + w) * ND + lane * 4;
        float4 v = *(const float4*)(captions + off);
        bf16x4 h = { (bf16)v.x, (bf16)v.y, (bf16)v.z, (bf16)v.w };
        *(bf16x4*)(capb + off) = h;
        float s = v.x*v.x + v.y*v.y + v.z*v.z + v.w*v.w;
        s += __shfl_xor(s, 1);  s += __shfl_xor(s, 2);  s += __shfl_xor(s, 4);
        s += __shfl_xor(s, 8);  s += __shfl_xor(s, 16); s += __shfl_xor(s, 32);
        if (lane == 0) w1g[c * NW + w] = LSE_SCALE / sqrtf(s);
    }
}

__device__ __forceinline__ bf16x8 ld_cvt_f32(const float* p, float& ss) {
    float4 lo = *(const float4*)p;
    float4 hi = *(const float4*)(p + 4);
    ss += lo.x*lo.x + lo.y*lo.y + lo.z*lo.z + lo.w*lo.w
        + hi.x*hi.x + hi.y*hi.y + hi.z*hi.z + hi.w*hi.w;
    bf16x8 r = { (bf16)lo.x, (bf16)lo.y, (bf16)lo.z, (bf16)lo.w,
                 (bf16)hi.x, (bf16)hi.y, (bf16)hi.z, (bf16)hi.w };
    return r;
}

// W-stage: softmax weights for one mt-tile -> IN-PLACE into acc[MT] + write to sP buffer.
#define STAGE_W(MT, BUF, W12) do {                                                      \
    _Pragma("unroll")                                                                   \
    for (int p = 0; p < 4; ++p) {                                                       \
        float a0v = acc[MT][0][p], a1v = acc[MT][1][p], a2v = acc[MT][2][p];            \
        float e0 = exp2f(__builtin_fmaf(c1[0], a0v, c2[0] * __builtin_fabsf(a0v)));     \
        float e1 = exp2f(__builtin_fmaf(c1[1], a1v, c2[1] * __builtin_fabsf(a1v)));     \
        float e2 = (l15 >= 12)                                                          \
            ? exp2f(__builtin_fmaf(c1[2], a2v, c2[2] * __builtin_fabsf(a2v)))           \
            : 0.f;                                        /* r=32..35 only */           \
        W12[p] = e0 * a0v + e1 * a1v + e2 * a2v;                                        \
        acc[MT][0][p] = e0; acc[MT][1][p] = e1; acc[MT][2][p] = e2;   /* in-place */    \
        int row = quad * 4 + p;                                                         \
        (BUF)[row * PSP + l15]      = (bf16)e0;                                         \
        (BUF)[row * PSP + 16 + l15] = (bf16)e1;                                         \
        if (l15 >= 12) (BUF)[row * PSP + rb2 + l15] = (bf16)e2;   /* cols 32..35 */     \
    }                                                                                   \
} while (0)

// R-stage: PV MFMA via Gram + epilogue. Reads BUF written >=1 full stage earlier
// (the write->read RAW latency is hidden by the interleaved stage's exp/MFMA work).
// setprio(1) around the MFMA cluster: independent waves (no barriers after B1) ->
// the attn-regime where T5 paid (+4-7%, m191); null on lockstep GEMM (m190).
#define STAGE_R(MT, BUF, W12) do {                                                      \
    const bf16* ap = (BUF) + l15 * PSP;                                                 \
    bf16x8 pa0 = *(const bf16x8*)(ap + quad * 8);                                       \
    bf16x8 pa1 = *(const bf16x8*)(ap + 32 + quad * 8);  /* cols>=36: finite x G-zeros */\
    f32x4 pg0 = {0,0,0,0}, pg1 = {0,0,0,0}, pg2 = {0,0,0,0};                            \
    {                                                                                   \
        bf16x8 t0 = *(const bf16x8*)&sG[(l15) * PG + quad * 8];                         \
        bf16x8 t1 = *(const bf16x8*)&sG[(l15) * PG + 32 + quad * 8];                    \
        bf16x8 t2 = *(const bf16x8*)&sG[(16 + l15) * PG + quad * 8];                    \
        bf16x8 t3 = *(const bf16x8*)&sG[(16 + l15) * PG + 32 + quad * 8];               \
        bf16x8 t4 = *(const bf16x8*)&sG[(rb2 + l15) * PG + quad * 8];                   \
        bf16x8 t5 = *(const bf16x8*)&sG[(rb2 + l15) * PG + 32 + quad * 8];              \
        __builtin_amdgcn_s_setprio(1);                                                  \
        pg0 = MFMA16(pa0, t0, pg0); pg0 = MFMA16(pa1, t1, pg0);                         \
        pg1 = MFMA16(pa0, t2, pg1); pg1 = MFMA16(pa1, t3, pg1);                         \
        pg2 = MFMA16(pa0, t4, pg2); pg2 = MFMA16(pa1, t5, pg2);                         \
        __builtin_amdgcn_s_setprio(0);                                                  \
    }                                                                                   \
    float4 wq = {0.f, 0.f, 0.f, 0.f};                                                   \
    if constexpr (USE_WS)                                                               \
        wq = *(const float4*)&w1g[(size_t)c * NW + (MT) * 16 + quad * 4];               \
    _Pragma("unroll")                                                                   \
    for (int p = 0; p < 4; ++p) {                                                       \
        float s2 = pg0[p] * acc[MT][0][p] + pg1[p] * acc[MT][1][p]                      \
                 + pg2[p] * acc[MT][2][p];                    /* acc holds e (f32) */   \
        s2 = dpp_add16(s2);                                                             \
        float w12 = dpp_add16(W12[p]);                                                  \
        float wf = USE_WS ? ((const float*)&wq)[p] : w1f[MT][p];                        \
        esum += exp2f(w12 * __frsqrt_rn(fmaxf(s2, 1e-16f)) * wf);                       \
    }                                                                                   \
} while (0)

// Ledger: R8 (W/R pipeline + in-place diet) = best, 115.6 us / 164.6 bench.
// R9 (cross-caption QK, dual acc) = regression (+36 regs -> occupancy 28%, spill 6.5MB)
// -> cross-caption ILP closed for good (3rd falsification). R10 = R8 verbatim +
// s_setprio(1) around QK and STAGE_R MFMA clusters (T5; independent-wave regime).
// Spill canary: WRITE_SIZE must stay ~132 KB.
template<bool USE_WS>
__global__ __attribute__((amdgpu_flat_work_group_size(256, 256), amdgpu_waves_per_eu(4, 8)))
void scan_main(const float* __restrict__ images,
               const float* __restrict__ captions,
               const bf16* __restrict__ capb,
               const float* __restrict__ w1g,
               float* __restrict__ out)
{
    __shared__ __align__(16) unsigned char smem[SMEM_TOTAL];
    bf16* sIb = (bf16*)(smem + OFF_IB);   // [r][d] image, 36 real rows only
    bf16* sG  = (bf16*)(smem + OFF_G);    // [r'][r] Gram, 36 rows x 72 cols (36..71 zero)

    const int tid  = threadIdx.x;
    const int wave = tid >> 6;
    const int lane = tid & 63;
    const int quad = lane >> 4;
    const int l15  = lane & 15;
    const int i    = blockIdx.x >> 4;
    const int c0   = (blockIdx.x & 15) * 16;  // chunk -> (chunk%8) XCD-affine captions

    bf16* bufA = (bf16*)(smem + OFF_P) + wave * (32 * PSP);   // two 16-row buffers
    bf16* bufB = bufA + 16 * PSP;

    const int rb2 = 20;   // r-tile bases {0,16,20}; tile 2 overlaps tile 1 on r=20..31

    // ---- init: stage image bf16, zero sG and sP+guard ----
    const float* gI = images + (size_t)i * NR * ND;
    #pragma unroll
    for (int k = 0; k < 9; ++k) {
        int t = tid + k * 256;               // 2304 float4
        int e = t * 4, r = e >> 8, d = e & 255;
        float4 v = *(const float4*)(gI + e);
        bf16x4 h = { (bf16)v.x, (bf16)v.y, (bf16)v.z, (bf16)v.w };
        *(bf16x4*)&sIb[r * PIB + d] = h;
    }
    {
        uint32_t* pG = (uint32_t*)sG;        // 1296 dwords
        #pragma unroll
        for (int k = 0; k < 6; ++k) { int x = tid + k * 256; if (x < 1296) pG[x] = 0u; }
        uint32_t* pP = (uint32_t*)(smem + OFF_P);   // sP buffers + guard: 3360 dwords
        #pragma unroll
        for (int k = 0; k < 14; ++k) { int x = tid + k * 256; if (x < 3360) pP[x] = 0u; }
        // cols 36..51 of each sP row are never written after this -> stay zero (k-pad safety)
    }
    __syncthreads();   // B0

    // ---- once: Gram G = I*I^T over overlapped m-tiles {0,16,20} (waves 0-2) ----
    if (wave < 3) {
        const int mb = (wave == 2) ? rb2 : wave * 16;
        f32x4 g0 = {0,0,0,0}, g1 = {0,0,0,0}, g2 = {0,0,0,0};
        #pragma unroll
        for (int ks = 0; ks < 8; ++ks) {
            bf16x8 a  = *(const bf16x8*)&sIb[(mb + l15)  * PIB + ks * 32 + quad * 8];
            bf16x8 b0 = *(const bf16x8*)&sIb[(l15)       * PIB + ks * 32 + quad * 8];
            bf16x8 b1 = *(const bf16x8*)&sIb[(16 + l15)  * PIB + ks * 32 + quad * 8];
            bf16x8 b2 = *(const bf16x8*)&sIb[(rb2 + l15) * PIB + ks * 32 + quad * 8];
            g0 = MFMA16(a, b0, g0); g1 = MFMA16(a, b1, g1); g2 = MFMA16(a, b2, g2);
        }
        // duplicate writes in overlap regions carry identical values (benign)
        #pragma unroll
        for (int p = 0; p < 4; ++p) {
            int m = mb + quad * 4 + p;
            sG[m * PG + l15]       = (bf16)g0[p];
            sG[m * PG + 16 + l15]  = (bf16)g1[p];
            sG[m * PG + rb2 + l15] = (bf16)g2[p];
        }
    }
    __syncthreads();   // B1: sG published. No further barriers.

    // ---- per-wave: 4 captions, everything in-wave ----
    for (int it = 0; it < 4; ++it) {
        const int c = c0 + wave * 4 + it;

        // ---- phase 1: raw logits attnT[w][r] = C_c . I^T ----
        f32x4 acc[3][3] = {};
        float ssc[3] = {0.f, 0.f, 0.f};
        float w1f[3][4] = {};                 // !USE_WS only (fallback path)
        const bf16*  ab   = USE_WS ? capb + ((size_t)c * NW + l15) * ND + quad * 8 : nullptr;
        const float* ab32 = USE_WS ? nullptr : captions + ((size_t)c * NW + l15) * ND + quad * 8;
        __builtin_amdgcn_s_setprio(1);        // MFMA-dense phase: bias CU scheduler
        #pragma unroll
        for (int ks = 0; ks < 8; ++ks) {
            bf16x8 a0, a1, a2;
            if (USE_WS) {
                a0 = *(const bf16x8*)(ab + ks * 32);
                a1 = *(const bf16x8*)(ab + 16 * ND + ks * 32);
                a2 = *(const bf16x8*)(ab + 32 * ND + ks * 32);
            } else {
                a0 = ld_cvt_f32(ab32 + ks * 32, ssc[0]);
                a1 = ld_cvt_f32(ab32 + 16 * ND + ks * 32, ssc[1]);
                a2 = ld_cvt_f32(ab32 + 32 * ND + ks * 32, ssc[2]);
            }
            bf16x8 b0 = *(const bf16x8*)&sIb[(l15)       * PIB + ks * 32 + quad * 8];
            bf16x8 b1 = *(const bf16x8*)&sIb[(16 + l15)  * PIB + ks * 32 + quad * 8];
            bf16x8 b2 = *(const bf16x8*)&sIb[(rb2 + l15) * PIB + ks * 32 + quad * 8];
            acc[0][0] = MFMA16(a0, b0, acc[0][0]);
            acc[1][0] = MFMA16(a1, b0, acc[1][0]);
            acc[2][0] = MFMA16(a2, b0, acc[2][0]);
            acc[0][1] = MFMA16(a0, b1, acc[0][1]);
            acc[1][1] = MFMA16(a1, b1, acc[1][1]);
            acc[2][1] = MFMA16(a2, b1, acc[2][1]);
            acc[0][2] = MFMA16(a0, b2, acc[0][2]);
            acc[1][2] = MFMA16(a1, b2, acc[1][2]);
            acc[2][2] = MFMA16(a2, b2, acc[2][2]);
        }
        __builtin_amdgcn_s_setprio(0);
        if (!USE_WS) {
            #pragma unroll
            for (int mt = 0; mt < 3; ++mt) {
                float s = ssc[mt];
                s += __shfl_xor(s, 16); s += __shfl_xor(s, 32);
                ssc[mt] = LSE_SCALE * __frsqrt_rn(fmaxf(s, 1e-16f));   // = LSE/w1
            }
            #pragma unroll
            for (int mt = 0; mt < 3; ++mt)
                #pragma unroll
                for (int p = 0; p < 4; ++p)
                    w1f[mt][p] = __shfl(ssc[mt], (lane & 48) + quad * 4 + p);
        }

        // ---- l2norm over w; nt=2 valid at l15>=12 (r=32..35) ----
        // fold 9*log2e*inv into the exp2 argument: exp2(c1*a + c2*|a|)
        float c1[3], c2[3];
        #pragma unroll
        for (int nt = 0; nt < 3; ++nt) {
            float s = 0.f;
            #pragma unroll
            for (int mt = 0; mt < 3; ++mt)
                #pragma unroll
                for (int p = 0; p < 4; ++p) { float t = lrelu(acc[mt][nt][p]); s += t * t; }
            s += __shfl_xor(s, 16); s += __shfl_xor(s, 32);       // sum over w-quads
            float inv = SOFT_SCALE * __frsqrt_rn(fmaxf(s, 1e-12f));
            c1[nt] = 0.55f * inv;
            c2[nt] = 0.45f * inv;
        }

        // ---- W/R pipeline over 2 buffers: every write->read RAW spans a full stage ----
        float esum = 0.f;
        float w12a[4], w12b[4], w12c[4];
        STAGE_W(0, bufA, w12a);
        STAGE_W(1, bufB, w12b);
        STAGE_R(0, bufA, w12a);       // bufA written 1 stage ago; W1's exps in the shadow
        STAGE_W(2, bufA, w12c);       // bufA free (R0's reads precede in-wave DS order)
        STAGE_R(1, bufB, w12b);
        STAGE_R(2, bufA, w12c);

        esum += __shfl_xor(esum, 16); esum += __shfl_xor(esum, 32);
        if (lane == 0) out[(size_t)i * NC + c] = logf(esum) * (1.0f / 6.0f);
    }
}

extern "C" void kernel_launch(void* const* d_in, const int* in_sizes, int n_in,
                              void* d_out, int out_size, void* d_ws, size_t ws_size,
                              hipStream_t stream) {
    const float* images   = (const float*)d_in[0];   // (128, 36, 256) fp32
    const float* captions = (const float*)d_in[1];   // (256, 48, 256) fp32
    float* out = (float*)d_out;                      // (128, 256) fp32

    const size_t need_w1  = (size_t)NC * NW * sizeof(float);   // 49152
    const size_t need_cap = (size_t)NC * NW * ND * 2;          // 6291456
    bool use_ws = ws_size >= need_w1 + need_cap;

    dim3 grid(2048), block(256);   // R2/R8 launch geometry (proven best)
    if (use_ws) {
        float* w1g = (float*)d_ws;
        bf16*  capb = (bf16*)((char*)d_ws + need_w1);
        hipLaunchKernelGGL(prep_kernel, dim3(1024), dim3(256), 0, stream, captions, capb, w1g);
        hipLaunchKernelGGL((scan_main<true>), grid, block, 0, stream, images, captions, capb, w1g, out);
    } else {
        hipLaunchKernelGGL((scan_main<false>), grid, block, 0, stream, images, captions,
                           (const bf16*)nullptr, (const float*)nullptr, out);
    }
}